// Round 1
// baseline (456.050 us; speedup 1.0000x reference)
//
#include <hip/hip_runtime.h>

// Cont_Loss: loss = sum((out[:,:,0:16:2] - target[:,:,1:16:2])^2) / (32*128*128 * 8)
//
// Layout: [B*C=256][W=16][H*Wd=16384] fp32.
// pair p in [0,2048):  out  float idx = p*32768 + i          (even w-slice)
//                      tgt  float idx = p*32768 + 16384 + i  (odd  w-slice)
// In float4 units: out = p*8192 + i4, tgt = p*8192 + 4096 + i4, i4 in [0,4096).

#define N4_TOTAL (2048u * 4096u)   // 8,388,608 float4 pairs
#define INV_NORM (1.0f / 4194304.0f)

__global__ __launch_bounds__(256) void cont_loss_kernel(
    const float* __restrict__ out_p,
    const float* __restrict__ tgt_p,
    float* __restrict__ result)
{
    const float4* __restrict__ o4 = (const float4*)out_p;
    const float4* __restrict__ t4 = (const float4*)tgt_p;

    float acc = 0.0f;
    const unsigned stride = gridDim.x * blockDim.x;
    for (unsigned g = blockIdx.x * blockDim.x + threadIdx.x; g < N4_TOTAL; g += stride) {
        unsigned pair = g >> 12;      // / 4096
        unsigned i4   = g & 4095u;
        float4 o = o4[pair * 8192u + i4];
        float4 t = t4[pair * 8192u + 4096u + i4];
        float dx = o.x - t.x;
        float dy = o.y - t.y;
        float dz = o.z - t.z;
        float dw = o.w - t.w;
        acc = fmaf(dx, dx, acc);
        acc = fmaf(dy, dy, acc);
        acc = fmaf(dz, dz, acc);
        acc = fmaf(dw, dw, acc);
    }

    // wave-64 shuffle reduction
    #pragma unroll
    for (int off = 32; off > 0; off >>= 1)
        acc += __shfl_down(acc, off, 64);

    __shared__ float wave_sums[4];   // 256 threads / 64 lanes
    const int lane = threadIdx.x & 63;
    const int wid  = threadIdx.x >> 6;
    if (lane == 0) wave_sums[wid] = acc;
    __syncthreads();

    if (threadIdx.x == 0) {
        float s = wave_sums[0] + wave_sums[1] + wave_sums[2] + wave_sums[3];
        atomicAdd(result, s * INV_NORM);  // device-scope by default on CDNA
    }
}

extern "C" void kernel_launch(void* const* d_in, const int* in_sizes, int n_in,
                              void* d_out, int out_size, void* d_ws, size_t ws_size,
                              hipStream_t stream)
{
    const float* out_p = (const float*)d_in[0];
    const float* tgt_p = (const float*)d_in[1];
    float* result = (float*)d_out;

    // d_out is poisoned to 0xAA before every launch — zero it (capture-safe).
    hipMemsetAsync(result, 0, sizeof(float), stream);

    // 2048 blocks (8 per CU) x 256 threads -> 16 float4-pairs per thread.
    cont_loss_kernel<<<2048, 256, 0, stream>>>(out_p, tgt_p, result);
}